// Round 3
// baseline (642.123 us; speedup 1.0000x reference)
//
#include <hip/hip_runtime.h>

// Problem constants (B=2,S=2048,D=1024,E=8,DFF=2048,top_k=2)
#define T_TOK 4096
#define DIM   1024
#define DFF   2048
#define NE    8
#define NR    7   // routed experts (E-1)
#define MAXNB 71  // max total routed row-blocks: 8192/128 + 7

typedef __bf16 bf16x8 __attribute__((ext_vector_type(8)));
typedef float  floatx4 __attribute__((ext_vector_type(4)));

__device__ __forceinline__ unsigned short f32_bf16(float f) {
  union { float f; unsigned int u; } v; v.f = f;
  unsigned int u = v.u;
  unsigned int r = (u + 0x7FFFu + ((u >> 16) & 1u)) >> 16;  // RNE
  return (unsigned short)r;
}

typedef __attribute__((address_space(3))) void lds_void_t;
typedef const __attribute__((address_space(1))) void g_void_t;

__device__ __forceinline__ void gld16(const void* g, void* l) {
  // async global->LDS, 16B/lane; global addr per-lane, LDS dest = wave-uniform base + lane*16
  __builtin_amdgcn_global_load_lds((g_void_t*)g, (lds_void_t*)l, 16, 0, 0);
}

// LDS tile layout (all GEMM kernels): physical chunk pg at byte addr row*64 + pg*16
// holds logical k-chunk (pg ^ ((row>>1)&3)).  Staged by gld16 with swizzled global
// fetch; read back with per-lane constant pkq = (lane>>4) ^ ((fr>>1)&3).
// Bank base for lanes fr=0..15: (fr&1)*16 + pkq*4 -> 2-way only (free, m136).

// ---------------- x fp32 -> bf16 ----------------
__global__ __launch_bounds__(256) void cvt_x_kernel(const float4* __restrict__ in,
                                                    ushort4* __restrict__ out) {
  int i = blockIdx.x * 256 + threadIdx.x;
  float4 v = in[i];
  ushort4 o;
  o.x = f32_bf16(v.x); o.y = f32_bf16(v.y);
  o.z = f32_bf16(v.z); o.w = f32_bf16(v.w);
  out[i] = o;
}

// ---------------- router: top-2 -> per-expert token lists ----------------
__global__ __launch_bounds__(256) void router_kernel(const float* __restrict__ x,
                                                     const float* __restrict__ rw,
                                                     const float* __restrict__ rb,
                                                     int* __restrict__ idx,
                                                     float* __restrict__ wsl,
                                                     int* __restrict__ cnt) {
  const int lane = threadIdx.x & 63;
  const int t = blockIdx.x * 4 + (threadIdx.x >> 6);  // one wave per token
  const float* xr = x + (size_t)t * DIM;
  float acc[NR];
#pragma unroll
  for (int e = 0; e < NR; e++) acc[e] = 0.f;
  for (int d = lane; d < DIM; d += 64) {
    float xv = xr[d];
#pragma unroll
    for (int e = 0; e < NR; e++) acc[e] += xv * rw[d * NR + e];
  }
#pragma unroll
  for (int off = 32; off > 0; off >>= 1) {
#pragma unroll
    for (int e = 0; e < NR; e++) acc[e] += __shfl_xor(acc[e], off, 64);
  }
  if (lane == 0) {
    float lg[NR];
    float m = -1e30f;
#pragma unroll
    for (int e = 0; e < NR; e++) { lg[e] = acc[e] + rb[e]; m = fmaxf(m, lg[e]); }
    float p[NR], s = 0.f;
#pragma unroll
    for (int e = 0; e < NR; e++) { p[e] = expf(lg[e] - m); s += p[e]; }
#pragma unroll
    for (int e = 0; e < NR; e++) p[e] /= s;
    int i1 = 0;
#pragma unroll
    for (int e = 1; e < NR; e++) if (p[e] > p[i1]) i1 = e;   // ties -> lowest index (jax)
    int i2 = (i1 == 0) ? 1 : 0;
#pragma unroll
    for (int e = 0; e < NR; e++) if (e != i1 && p[e] > p[i2]) i2 = e;
    float w1 = p[i1], w2 = p[i2], sw = w1 + w2;
    int s1 = atomicAdd(&cnt[i1], 1);
    idx[i1 * 4096 + s1] = t; wsl[i1 * 4096 + s1] = w1 / sw;
    int s2 = atomicAdd(&cnt[i2], 1);
    idx[i2 * 4096 + s2] = t; wsl[i2 * 4096 + s2] = w2 / sw;
  }
}

// ---------------- schedule: block -> (expert, row-block, slot-base) ----------------
__global__ __launch_bounds__(256) void sched_kernel(const int* __restrict__ cnt,
                                                    int* __restrict__ idx,
                                                    float* __restrict__ wsl,
                                                    int4* __restrict__ schedM,
                                                    int4* __restrict__ schedP) {
  __shared__ int nb[NR], pref[NR];
  if (threadIdx.x == 0) {
    int p = 0;
    for (int e = 0; e < NR; e++) { int c = cnt[e]; int n = (c + 127) >> 7; nb[e] = n; pref[e] = p; p += n; }
  }
  __syncthreads();
  // pad token lists to a multiple of 128 with (token 0, weight 0)
  for (int e = 0; e < NR; e++) {
    int c = cnt[e], top = nb[e] * 128;
    for (int i = c + (int)threadIdx.x; i < top; i += 256) { idx[e * 4096 + i] = 0; wsl[e * 4096 + i] = 0.f; }
  }
  const int NB = pref[NR - 1] + nb[NR - 1];
  for (int y = threadIdx.x; y < MAXNB; y += 256) {
    int4 ent; ent.x = -1; ent.y = 0; ent.z = 0; ent.w = 0;
    if (y < NB) {
#pragma unroll
      for (int e = 0; e < NR; e++)
        if (y >= pref[e] && y < pref[e] + nb[e]) { ent.x = e; ent.y = y - pref[e]; ent.z = y * 128; }
    }
    schedM[y] = ent;
  }
  for (int i = threadIdx.x; i < NR * 32; i += 256) {
    int e = i >> 5, rb = i & 31;
    int4 ent; ent.w = 0;
    if (rb < nb[e]) { ent.x = e; ent.y = rb; ent.z = rb * 128; }
    else            { ent.x = -1; ent.y = 0; ent.z = 0; }
    schedP[i] = ent;
  }
}

// ---------------- weight transpose + fp32->bf16 (4B/lane writes) ----------------
__global__ __launch_bounds__(256) void transpose_cvt_kernel(
    const float* __restrict__ wg, const float* __restrict__ wu, const float* __restrict__ wd,
    unsigned short* __restrict__ wgt, unsigned short* __restrict__ wut,
    unsigned short* __restrict__ wdt) {
  __shared__ float tile[64][33];
  const int z = blockIdx.z;
  const float* src; unsigned short* dst; int R, C;
  if (z < 8)       { src = wg + (size_t)z * DIM * DFF;        dst = wgt + (size_t)z * DIM * DFF;        R = DIM; C = DFF; }
  else if (z < 16) { src = wu + (size_t)(z - 8) * DIM * DFF;  dst = wut + (size_t)(z - 8) * DIM * DFF;  R = DIM; C = DFF; }
  else             { src = wd + (size_t)(z - 16) * DFF * DIM; dst = wdt + (size_t)(z - 16) * DFF * DIM; R = DFF; C = DIM; }
  const int c0 = blockIdx.x * 32, r0 = blockIdx.y * 64;
  if (c0 >= C || r0 >= R) return;
  const int tx = threadIdx.x & 31, ty = threadIdx.x >> 5;
#pragma unroll
  for (int j = ty; j < 64; j += 8)
    tile[j][tx] = src[(size_t)(r0 + j) * C + c0 + tx];
  __syncthreads();
#pragma unroll
  for (int j = ty; j < 32; j += 8) {
    unsigned int lo = f32_bf16(tile[2 * tx][j]);
    unsigned int hi = f32_bf16(tile[2 * tx + 1][j]);
    *(unsigned int*)(dst + (size_t)(c0 + j) * R + r0 + 2 * tx) = lo | (hi << 16);
  }
}

// ---------------- GEMM1 dense (expert 0): h = silu(x@wg0)*(x@wu0) ----------------
__global__ __launch_bounds__(256) void gemm1_e0_kernel(
    const unsigned short* __restrict__ xb, const unsigned short* __restrict__ wgt_e,
    const unsigned short* __restrict__ wut_e, unsigned short* __restrict__ h) {
  __shared__ unsigned short As[128 * 32];
  __shared__ unsigned short Bg[64 * 32];
  __shared__ unsigned short Bu[64 * 32];
  const int tid = threadIdx.x, lane = tid & 63, wid = tid >> 6;
  const int m0 = blockIdx.y * 128, n0 = blockIdx.x * 64;
  const int wm = (wid >> 1) * 64, wn = (wid & 1) * 32;
  floatx4 accg[4][2], accu[4][2];
  const floatx4 z4 = {0.f, 0.f, 0.f, 0.f};
#pragma unroll
  for (int i = 0; i < 4; i++)
#pragma unroll
    for (int j = 0; j < 2; j++) { accg[i][j] = z4; accu[i][j] = z4; }
  const int srow = tid >> 2;
  const int scol = (((tid & 3) ^ ((srow >> 1) & 3))) * 8;   // swizzled k-chunk fetch
  const unsigned short* ap0 = xb + (size_t)(m0 + srow) * DIM + scol;
  const unsigned short* ap1 = ap0 + (size_t)64 * DIM;
  const unsigned short* bgp = wgt_e + (size_t)(n0 + srow) * DIM + scol;
  const unsigned short* bup = wut_e + (size_t)(n0 + srow) * DIM + scol;
  unsigned short* as0 = As + tid * 8;
  unsigned short* as1 = As + (256 + tid) * 8;
  unsigned short* bgl = Bg + tid * 8;
  unsigned short* bul = Bu + tid * 8;
  const int fr = lane & 15;
  const int pkq = (((lane >> 4) ^ ((fr >> 1) & 3))) * 8;    // per-lane constant
  for (int k0 = 0; k0 < DIM; k0 += 32) {
    __syncthreads();
    gld16(ap0 + k0, as0); gld16(ap1 + k0, as1);
    gld16(bgp + k0, bgl); gld16(bup + k0, bul);
    __syncthreads();
    bf16x8 af[4], bgf[2], buf2[2];
#pragma unroll
    for (int mi = 0; mi < 4; mi++) af[mi] = *(const bf16x8*)(As + (wm + mi * 16 + fr) * 32 + pkq);
#pragma unroll
    for (int ni = 0; ni < 2; ni++) {
      bgf[ni]  = *(const bf16x8*)(Bg + (wn + ni * 16 + fr) * 32 + pkq);
      buf2[ni] = *(const bf16x8*)(Bu + (wn + ni * 16 + fr) * 32 + pkq);
    }
#pragma unroll
    for (int mi = 0; mi < 4; mi++)
#pragma unroll
      for (int ni = 0; ni < 2; ni++) {
        accg[mi][ni] = __builtin_amdgcn_mfma_f32_16x16x32_bf16(af[mi], bgf[ni], accg[mi][ni], 0, 0, 0);
        accu[mi][ni] = __builtin_amdgcn_mfma_f32_16x16x32_bf16(af[mi], buf2[ni], accu[mi][ni], 0, 0, 0);
      }
  }
  const int rb0 = wm + (lane >> 4) * 4;
  const int cb0 = n0 + wn + fr;
#pragma unroll
  for (int mi = 0; mi < 4; mi++)
#pragma unroll
    for (int ni = 0; ni < 2; ni++)
#pragma unroll
      for (int r = 0; r < 4; r++) {
        int row = m0 + rb0 + mi * 16 + r;
        int col = cb0 + ni * 16;
        float g = accg[mi][ni][r], u = accu[mi][ni][r];
        float hv = (g / (1.f + __expf(-g))) * u;
        h[(size_t)row * DFF + col] = f32_bf16(hv);
      }
}

// ---------------- GEMM1 routed (gathered rows via sched table) ----------------
__global__ __launch_bounds__(256) void gemm1_routed_kernel(
    const unsigned short* __restrict__ xb, const unsigned short* __restrict__ wgt,
    const unsigned short* __restrict__ wut, const int* __restrict__ idx,
    const int4* __restrict__ sched, unsigned short* __restrict__ h) {
  const int4 ent = sched[blockIdx.y];
  if (ent.x < 0) return;
  const int e = ent.x, rblk = ent.y, sb = ent.z;
  __shared__ unsigned short As[128 * 32];
  __shared__ unsigned short Bg[64 * 32];
  __shared__ unsigned short Bu[64 * 32];
  const int tid = threadIdx.x, lane = tid & 63, wid = tid >> 6;
  const int n0 = blockIdx.x * 64;
  const int wm = (wid >> 1) * 64, wn = (wid & 1) * 32;
  floatx4 accg[4][2], accu[4][2];
  const floatx4 z4 = {0.f, 0.f, 0.f, 0.f};
#pragma unroll
  for (int i = 0; i < 4; i++)
#pragma unroll
    for (int j = 0; j < 2; j++) { accg[i][j] = z4; accu[i][j] = z4; }
  const unsigned short* wgt_e = wgt + (size_t)(e + 1) * DIM * DFF;
  const unsigned short* wut_e = wut + (size_t)(e + 1) * DIM * DFF;
  const int srow = tid >> 2;
  const int scol = (((tid & 3) ^ ((srow >> 1) & 3))) * 8;
  const int tok0 = idx[e * 4096 + rblk * 128 + srow];
  const int tok1 = idx[e * 4096 + rblk * 128 + srow + 64];
  const unsigned short* ap0 = xb + (size_t)tok0 * DIM + scol;
  const unsigned short* ap1 = xb + (size_t)tok1 * DIM + scol;
  const unsigned short* bgp = wgt_e + (size_t)(n0 + srow) * DIM + scol;
  const unsigned short* bup = wut_e + (size_t)(n0 + srow) * DIM + scol;
  unsigned short* as0 = As + tid * 8;
  unsigned short* as1 = As + (256 + tid) * 8;
  unsigned short* bgl = Bg + tid * 8;
  unsigned short* bul = Bu + tid * 8;
  const int fr = lane & 15;
  const int pkq = (((lane >> 4) ^ ((fr >> 1) & 3))) * 8;
  for (int k0 = 0; k0 < DIM; k0 += 32) {
    __syncthreads();
    gld16(ap0 + k0, as0); gld16(ap1 + k0, as1);
    gld16(bgp + k0, bgl); gld16(bup + k0, bul);
    __syncthreads();
    bf16x8 af[4], bgf[2], buf2[2];
#pragma unroll
    for (int mi = 0; mi < 4; mi++) af[mi] = *(const bf16x8*)(As + (wm + mi * 16 + fr) * 32 + pkq);
#pragma unroll
    for (int ni = 0; ni < 2; ni++) {
      bgf[ni]  = *(const bf16x8*)(Bg + (wn + ni * 16 + fr) * 32 + pkq);
      buf2[ni] = *(const bf16x8*)(Bu + (wn + ni * 16 + fr) * 32 + pkq);
    }
#pragma unroll
    for (int mi = 0; mi < 4; mi++)
#pragma unroll
      for (int ni = 0; ni < 2; ni++) {
        accg[mi][ni] = __builtin_amdgcn_mfma_f32_16x16x32_bf16(af[mi], bgf[ni], accg[mi][ni], 0, 0, 0);
        accu[mi][ni] = __builtin_amdgcn_mfma_f32_16x16x32_bf16(af[mi], buf2[ni], accu[mi][ni], 0, 0, 0);
      }
  }
  const int rb0 = wm + (lane >> 4) * 4;
  const int cb0 = n0 + wn + fr;
#pragma unroll
  for (int mi = 0; mi < 4; mi++)
#pragma unroll
    for (int ni = 0; ni < 2; ni++)
#pragma unroll
      for (int r = 0; r < 4; r++) {
        int lrow = rb0 + mi * 16 + r;
        int col = cb0 + ni * 16;
        float g = accg[mi][ni][r], u = accu[mi][ni][r];
        float hv = (g / (1.f + __expf(-g))) * u;
        h[(size_t)(sb + lrow) * DFF + col] = f32_bf16(hv);
      }
}

// ---------------- GEMM2 dense (expert 0): out = h @ wd0 (init) ----------------
__global__ __launch_bounds__(256) void gemm2_e0_kernel(
    const unsigned short* __restrict__ h, const unsigned short* __restrict__ wdt0,
    float* __restrict__ out) {
  __shared__ unsigned short As[128 * 32];
  __shared__ unsigned short Bs[128 * 32];
  const int tid = threadIdx.x, lane = tid & 63, wid = tid >> 6;
  const int m0 = blockIdx.y * 128, n0 = blockIdx.x * 128;
  const int wm = (wid >> 1) * 64, wn = (wid & 1) * 64;
  floatx4 acc[4][4];
  const floatx4 z4 = {0.f, 0.f, 0.f, 0.f};
#pragma unroll
  for (int i = 0; i < 4; i++)
#pragma unroll
    for (int j = 0; j < 4; j++) acc[i][j] = z4;
  const int srow = tid >> 2;
  const int scol = (((tid & 3) ^ ((srow >> 1) & 3))) * 8;
  const unsigned short* ap0 = h + (size_t)(m0 + srow) * DFF + scol;
  const unsigned short* ap1 = ap0 + (size_t)64 * DFF;
  const unsigned short* bp0 = wdt0 + (size_t)(n0 + srow) * DFF + scol;
  const unsigned short* bp1 = bp0 + (size_t)64 * DFF;
  unsigned short* as0 = As + tid * 8;
  unsigned short* as1 = As + (256 + tid) * 8;
  unsigned short* bs0 = Bs + tid * 8;
  unsigned short* bs1 = Bs + (256 + tid) * 8;
  const int fr = lane & 15;
  const int pkq = (((lane >> 4) ^ ((fr >> 1) & 3))) * 8;
  for (int k0 = 0; k0 < DFF; k0 += 32) {
    __syncthreads();
    gld16(ap0 + k0, as0); gld16(ap1 + k0, as1);
    gld16(bp0 + k0, bs0); gld16(bp1 + k0, bs1);
    __syncthreads();
    bf16x8 af[4], bf[4];
#pragma unroll
    for (int mi = 0; mi < 4; mi++) af[mi] = *(const bf16x8*)(As + (wm + mi * 16 + fr) * 32 + pkq);
#pragma unroll
    for (int ni = 0; ni < 4; ni++) bf[ni] = *(const bf16x8*)(Bs + (wn + ni * 16 + fr) * 32 + pkq);
#pragma unroll
    for (int mi = 0; mi < 4; mi++)
#pragma unroll
      for (int ni = 0; ni < 4; ni++)
        acc[mi][ni] = __builtin_amdgcn_mfma_f32_16x16x32_bf16(af[mi], bf[ni], acc[mi][ni], 0, 0, 0);
  }
  const int rb0 = wm + (lane >> 4) * 4;
  const int cb0 = n0 + wn + fr;
#pragma unroll
  for (int mi = 0; mi < 4; mi++)
#pragma unroll
    for (int ni = 0; ni < 4; ni++)
#pragma unroll
      for (int r = 0; r < 4; r++) {
        int row = m0 + rb0 + mi * 16 + r;
        int col = cb0 + ni * 16;
        out[(size_t)row * DIM + col] = acc[mi][ni][r];
      }
}

// ---------------- GEMM2 routed: out[tok] += w_slot * (h_slot @ wd_e) ----------------
__global__ __launch_bounds__(256) void gemm2_routed_kernel(
    const unsigned short* __restrict__ h, const unsigned short* __restrict__ wdt,
    const int* __restrict__ idx, const float* __restrict__ wsl,
    const int4* __restrict__ sched, float* __restrict__ out) {
  const int4 ent = sched[blockIdx.y];
  if (ent.x < 0) return;
  const int e = ent.x, rblk = ent.y, sb = ent.z;
  __shared__ unsigned short As[128 * 32];
  __shared__ unsigned short Bs[128 * 32];
  const int tid = threadIdx.x, lane = tid & 63, wid = tid >> 6;
  const int n0 = blockIdx.x * 128;
  const int wm = (wid >> 1) * 64, wn = (wid & 1) * 64;
  floatx4 acc[4][4];
  const floatx4 z4 = {0.f, 0.f, 0.f, 0.f};
#pragma unroll
  for (int i = 0; i < 4; i++)
#pragma unroll
    for (int j = 0; j < 4; j++) acc[i][j] = z4;
  const unsigned short* wdt_e = wdt + (size_t)(e + 1) * DFF * DIM;
  const int srow = tid >> 2;
  const int scol = (((tid & 3) ^ ((srow >> 1) & 3))) * 8;
  const unsigned short* ap0 = h + (size_t)(sb + srow) * DFF + scol;
  const unsigned short* ap1 = ap0 + (size_t)64 * DFF;
  const unsigned short* bp0 = wdt_e + (size_t)(n0 + srow) * DFF + scol;
  const unsigned short* bp1 = bp0 + (size_t)64 * DFF;
  unsigned short* as0 = As + tid * 8;
  unsigned short* as1 = As + (256 + tid) * 8;
  unsigned short* bs0 = Bs + tid * 8;
  unsigned short* bs1 = Bs + (256 + tid) * 8;
  const int fr = lane & 15;
  const int pkq = (((lane >> 4) ^ ((fr >> 1) & 3))) * 8;
  for (int k0 = 0; k0 < DFF; k0 += 32) {
    __syncthreads();
    gld16(ap0 + k0, as0); gld16(ap1 + k0, as1);
    gld16(bp0 + k0, bs0); gld16(bp1 + k0, bs1);
    __syncthreads();
    bf16x8 af[4], bf[4];
#pragma unroll
    for (int mi = 0; mi < 4; mi++) af[mi] = *(const bf16x8*)(As + (wm + mi * 16 + fr) * 32 + pkq);
#pragma unroll
    for (int ni = 0; ni < 4; ni++) bf[ni] = *(const bf16x8*)(Bs + (wn + ni * 16 + fr) * 32 + pkq);
#pragma unroll
    for (int mi = 0; mi < 4; mi++)
#pragma unroll
      for (int ni = 0; ni < 4; ni++)
        acc[mi][ni] = __builtin_amdgcn_mfma_f32_16x16x32_bf16(af[mi], bf[ni], acc[mi][ni], 0, 0, 0);
  }
  const int rb0 = wm + (lane >> 4) * 4;
  const int cb0 = n0 + wn + fr;
#pragma unroll
  for (int mi = 0; mi < 4; mi++)
#pragma unroll
    for (int r = 0; r < 4; r++) {
      int lrow = rb0 + mi * 16 + r;
      int gi = e * 4096 + rblk * 128 + lrow;
      int tok = idx[gi];
      float s = wsl[gi];
      if (s != 0.f) {
#pragma unroll
        for (int ni = 0; ni < 4; ni++)
          atomicAdd(&out[(size_t)tok * DIM + cb0 + ni * 16], s * acc[mi][ni][r]);
      }
    }
}

extern "C" void kernel_launch(void* const* d_in, const int* in_sizes, int n_in,
                              void* d_out, int out_size, void* d_ws, size_t ws_size,
                              hipStream_t stream) {
  const float* x  = (const float*)d_in[0];
  const float* rw = (const float*)d_in[1];
  const float* rb = (const float*)d_in[2];
  const float* wg = (const float*)d_in[3];
  const float* wu = (const float*)d_in[4];
  const float* wd = (const float*)d_in[5];
  float* out = (float*)d_out;

  const bool big = ws_size >= (size_t)146600000;
  const size_t H_ROWS = big ? (size_t)(MAXNB * 128) : (size_t)4096;

  char* p = (char*)d_ws;
  unsigned short* xb  = (unsigned short*)p; p += (size_t)T_TOK * DIM * 2;
  unsigned short* h   = (unsigned short*)p; p += H_ROWS * DFF * 2;
  unsigned short* wgt = (unsigned short*)p; p += (size_t)NE * DIM * DFF * 2;
  unsigned short* wut = (unsigned short*)p; p += (size_t)NE * DIM * DFF * 2;
  unsigned short* wdt = (unsigned short*)p; p += (size_t)NE * DIM * DFF * 2;
  int*   idx = (int*)p;   p += (size_t)NR * 4096 * 4;
  float* wsl = (float*)p; p += (size_t)NR * 4096 * 4;
  int*   cnt = (int*)p;   p += 64;
  int4*  schedM = (int4*)p; p += 2048;
  int4*  schedP = (int4*)p; p += 4096;

  cvt_x_kernel<<<dim3(T_TOK * DIM / 4 / 256), 256, 0, stream>>>((const float4*)x, (ushort4*)xb);
  hipMemsetAsync(cnt, 0, 64, stream);
  router_kernel<<<dim3(T_TOK / 4), 256, 0, stream>>>(x, rw, rb, idx, wsl, cnt);
  sched_kernel<<<dim3(1), 256, 0, stream>>>(cnt, idx, wsl, schedM, schedP);
  transpose_cvt_kernel<<<dim3(64, 32, 24), 256, 0, stream>>>(wg, wu, wd, wgt, wut, wdt);

  gemm1_e0_kernel<<<dim3(DFF / 64, T_TOK / 128), 256, 0, stream>>>(xb, wgt, wut, h);
  gemm2_e0_kernel<<<dim3(DIM / 128, T_TOK / 128), 256, 0, stream>>>(h, wdt, out);

  if (big) {
    gemm1_routed_kernel<<<dim3(DFF / 64, MAXNB), 256, 0, stream>>>(xb, wgt, wut, idx, schedM, h);
    gemm2_routed_kernel<<<dim3(DIM / 128, MAXNB), 256, 0, stream>>>(h, wdt, idx, wsl, schedM, out);
  } else {
    for (int r = 0; r < NR; r++) {
      gemm1_routed_kernel<<<dim3(DFF / 64, 32), 256, 0, stream>>>(xb, wgt, wut, idx, schedP + r * 32, h);
      gemm2_routed_kernel<<<dim3(DIM / 128, 32), 256, 0, stream>>>(h, wdt, idx, wsl, schedP + r * 32, out);
    }
  }
}

// Round 4
// 627.227 us; speedup vs baseline: 1.0237x; 1.0237x over previous
//
#include <hip/hip_runtime.h>

// Problem constants (B=2,S=2048,D=1024,E=8,DFF=2048,top_k=2)
#define T_TOK 4096
#define DIM   1024
#define DFF   2048
#define NE    8
#define NR    7    // routed experts (E-1)
#define MAXNB 71   // max routed row-blocks: 8192/128 + 7
#define NY    (32 + MAXNB)   // unified sched entries: 32 e0 + routed

typedef __bf16 bf16x8 __attribute__((ext_vector_type(8)));
typedef float  floatx4 __attribute__((ext_vector_type(4)));

__device__ __forceinline__ unsigned short f32_bf16(float f) {
  union { float f; unsigned int u; } v; v.f = f;
  unsigned int u = v.u;
  unsigned int r = (u + 0x7FFFu + ((u >> 16) & 1u)) >> 16;  // RNE
  return (unsigned short)r;
}

typedef __attribute__((address_space(3))) void lds_void_t;
typedef const __attribute__((address_space(1))) void g_void_t;

__device__ __forceinline__ void gld16(const void* g, void* l) {
  // async global->LDS, 16B/lane; LDS dest = wave-uniform base + lane*16 (m104)
  __builtin_amdgcn_global_load_lds((g_void_t*)g, (lds_void_t*)l, 16, 0, 0);
}

// ---------------- x fp32 -> bf16 ----------------
__global__ __launch_bounds__(256) void cvt_x_kernel(const float4* __restrict__ in,
                                                    ushort4* __restrict__ out) {
  int i = blockIdx.x * 256 + threadIdx.x;
  float4 v = in[i];
  ushort4 o;
  o.x = f32_bf16(v.x); o.y = f32_bf16(v.y);
  o.z = f32_bf16(v.z); o.w = f32_bf16(v.w);
  out[i] = o;
}

// ---------------- router: top-2 -> slot lists (identity section + per-expert) ----------------
__global__ __launch_bounds__(256) void router_kernel(const float* __restrict__ x,
                                                     const float* __restrict__ rw,
                                                     const float* __restrict__ rb,
                                                     int* __restrict__ idxAll,
                                                     float* __restrict__ wslAll,
                                                     int* __restrict__ cnt) {
  const int lane = threadIdx.x & 63;
  const int t = blockIdx.x * 4 + (threadIdx.x >> 6);  // one wave per token
  const float* xr = x + (size_t)t * DIM;
  float acc[NR];
#pragma unroll
  for (int e = 0; e < NR; e++) acc[e] = 0.f;
  for (int d = lane; d < DIM; d += 64) {
    float xv = xr[d];
#pragma unroll
    for (int e = 0; e < NR; e++) acc[e] += xv * rw[d * NR + e];
  }
#pragma unroll
  for (int off = 32; off > 0; off >>= 1) {
#pragma unroll
    for (int e = 0; e < NR; e++) acc[e] += __shfl_xor(acc[e], off, 64);
  }
  if (lane == 0) {
    // identity section for always-on expert 0
    idxAll[t] = t; wslAll[t] = 1.0f;
    float lg[NR];
    float m = -1e30f;
#pragma unroll
    for (int e = 0; e < NR; e++) { lg[e] = acc[e] + rb[e]; m = fmaxf(m, lg[e]); }
    float p[NR], s = 0.f;
#pragma unroll
    for (int e = 0; e < NR; e++) { p[e] = expf(lg[e] - m); s += p[e]; }
#pragma unroll
    for (int e = 0; e < NR; e++) p[e] /= s;
    int i1 = 0;
#pragma unroll
    for (int e = 1; e < NR; e++) if (p[e] > p[i1]) i1 = e;   // ties -> lowest index (jax)
    int i2 = (i1 == 0) ? 1 : 0;
#pragma unroll
    for (int e = 0; e < NR; e++) if (e != i1 && p[e] > p[i2]) i2 = e;
    float w1 = p[i1], w2 = p[i2], sw = w1 + w2;
    int s1 = atomicAdd(&cnt[i1], 1);
    idxAll[4096 + i1 * 4096 + s1] = t; wslAll[4096 + i1 * 4096 + s1] = w1 / sw;
    int s2 = atomicAdd(&cnt[i2], 1);
    idxAll[4096 + i2 * 4096 + s2] = t; wslAll[4096 + i2 * 4096 + s2] = w2 / sw;
  }
}

// ---------------- schedule tables ----------------
// schedAll[0..31]   : expert-0 blocks (weights index 0, identity idx, slots y*128)
// schedAll[32..102] : routed blocks packed by prefix (slots rsb + y*128)
// schedP[e*32+rb]   : per-expert tables (fallback path)
// ent = (weightIdx 0..7 or -1, idx/wsl offset, h slot base, 0)
__global__ __launch_bounds__(256) void sched_kernel(const int* __restrict__ cnt,
                                                    int* __restrict__ idxAll,
                                                    float* __restrict__ wslAll,
                                                    int4* __restrict__ schedAll,
                                                    int4* __restrict__ schedP,
                                                    int rsb) {
  __shared__ int nb[NR], pref[NR];
  if (threadIdx.x == 0) {
    int p = 0;
    for (int e = 0; e < NR; e++) { int c = cnt[e]; int n = (c + 127) >> 7; nb[e] = n; pref[e] = p; p += n; }
  }
  __syncthreads();
  for (int e = 0; e < NR; e++) {
    int c = cnt[e], top = nb[e] * 128;
    for (int i = c + (int)threadIdx.x; i < top; i += 256) {
      idxAll[4096 + e * 4096 + i] = 0; wslAll[4096 + e * 4096 + i] = 0.f;
    }
  }
  const int NBtot = pref[NR - 1] + nb[NR - 1];
  for (int y = threadIdx.x; y < 32; y += 256) {
    int4 ent; ent.x = 0; ent.y = y * 128; ent.z = y * 128; ent.w = 0;
    schedAll[y] = ent;
  }
  for (int y = threadIdx.x; y < MAXNB; y += 256) {
    int4 ent; ent.x = -1; ent.y = 0; ent.z = 0; ent.w = 0;
    if (y < NBtot) {
#pragma unroll
      for (int e = 0; e < NR; e++)
        if (y >= pref[e] && y < pref[e] + nb[e]) {
          int rb2 = y - pref[e];
          ent.x = e + 1; ent.y = 4096 + e * 4096 + rb2 * 128; ent.z = rsb + y * 128;
        }
    }
    schedAll[32 + y] = ent;
  }
  for (int i = threadIdx.x; i < NR * 32; i += 256) {
    int e = i >> 5, rb2 = i & 31;
    int4 ent; ent.w = 0;
    if (rb2 < nb[e]) { ent.x = e + 1; ent.y = 4096 + e * 4096 + rb2 * 128; ent.z = rsb + rb2 * 128; }
    else             { ent.x = -1; ent.y = 0; ent.z = 0; }
    schedP[i] = ent;
  }
}

// ---------------- weight transpose + fp32->bf16 (4B/lane writes) ----------------
__global__ __launch_bounds__(256) void transpose_cvt_kernel(
    const float* __restrict__ wg, const float* __restrict__ wu, const float* __restrict__ wd,
    unsigned short* __restrict__ wgt, unsigned short* __restrict__ wut,
    unsigned short* __restrict__ wdt) {
  __shared__ float tile[64][33];
  const int z = blockIdx.z;
  const float* src; unsigned short* dst; int R, C;
  if (z < 8)       { src = wg + (size_t)z * DIM * DFF;        dst = wgt + (size_t)z * DIM * DFF;        R = DIM; C = DFF; }
  else if (z < 16) { src = wu + (size_t)(z - 8) * DIM * DFF;  dst = wut + (size_t)(z - 8) * DIM * DFF;  R = DIM; C = DFF; }
  else             { src = wd + (size_t)(z - 16) * DFF * DIM; dst = wdt + (size_t)(z - 16) * DFF * DIM; R = DFF; C = DIM; }
  const int c0 = blockIdx.x * 32, r0 = blockIdx.y * 64;
  if (c0 >= C || r0 >= R) return;
  const int tx = threadIdx.x & 31, ty = threadIdx.x >> 5;
#pragma unroll
  for (int j = ty; j < 64; j += 8)
    tile[j][tx] = src[(size_t)(r0 + j) * C + c0 + tx];
  __syncthreads();
#pragma unroll
  for (int j = ty; j < 32; j += 8) {
    unsigned int lo = f32_bf16(tile[2 * tx][j]);
    unsigned int hi = f32_bf16(tile[2 * tx + 1][j]);
    *(unsigned int*)(dst + (size_t)(c0 + j) * R + r0 + 2 * tx) = lo | (hi << 16);
  }
}

// ---------------- unified GEMM1: h[slot] = silu(x[tok]@wg_e)*(x[tok]@wu_e) ----------------
// BM=128, BN=64 per matrix, BK=32; 4 waves 2x2 of 64x32-per-matrix wave tiles.
__global__ __launch_bounds__(256) void gemm1_kernel(
    const unsigned short* __restrict__ xb, const unsigned short* __restrict__ wgt,
    const unsigned short* __restrict__ wut, const int* __restrict__ idxAll,
    const int4* __restrict__ sched, unsigned short* __restrict__ h) {
  const int4 ent = sched[blockIdx.y];
  if (ent.x < 0) return;
  __shared__ unsigned short As[128 * 32];
  __shared__ unsigned short Bg[64 * 32];
  __shared__ unsigned short Bu[64 * 32];
  const int tid = threadIdx.x, lane = tid & 63, wid = tid >> 6;
  const int n0 = blockIdx.x * 64;
  const int wm = (wid >> 1) * 64, wn = (wid & 1) * 32;
  floatx4 accg[4][2], accu[4][2];
  const floatx4 z4 = {0.f, 0.f, 0.f, 0.f};
#pragma unroll
  for (int i = 0; i < 4; i++)
#pragma unroll
    for (int j = 0; j < 2; j++) { accg[i][j] = z4; accu[i][j] = z4; }
  const unsigned short* wgt_e = wgt + (size_t)ent.x * DIM * DFF;
  const unsigned short* wut_e = wut + (size_t)ent.x * DIM * DFF;
  const int srow = tid >> 2, scol = (tid & 3) * 8;
  const int tok0 = idxAll[ent.y + srow];
  const int tok1 = idxAll[ent.y + srow + 64];
  const unsigned short* ap0 = xb + (size_t)tok0 * DIM + scol;
  const unsigned short* ap1 = xb + (size_t)tok1 * DIM + scol;
  const unsigned short* bgp = wgt_e + (size_t)(n0 + srow) * DIM + scol;
  const unsigned short* bup = wut_e + (size_t)(n0 + srow) * DIM + scol;
  unsigned short* as0 = As + tid * 8;
  unsigned short* as1 = As + (256 + tid) * 8;
  unsigned short* bgl = Bg + tid * 8;
  unsigned short* bul = Bu + tid * 8;
  const int fr = lane & 15, kq = (lane >> 4) * 8;
  for (int k0 = 0; k0 < DIM; k0 += 32) {
    __syncthreads();
    gld16(ap0 + k0, as0); gld16(ap1 + k0, as1);
    gld16(bgp + k0, bgl); gld16(bup + k0, bul);
    __syncthreads();
    bf16x8 af[4], bgf[2], buf2[2];
#pragma unroll
    for (int mi = 0; mi < 4; mi++) af[mi] = *(const bf16x8*)(As + (wm + mi * 16 + fr) * 32 + kq);
#pragma unroll
    for (int ni = 0; ni < 2; ni++) {
      bgf[ni]  = *(const bf16x8*)(Bg + (wn + ni * 16 + fr) * 32 + kq);
      buf2[ni] = *(const bf16x8*)(Bu + (wn + ni * 16 + fr) * 32 + kq);
    }
#pragma unroll
    for (int mi = 0; mi < 4; mi++)
#pragma unroll
      for (int ni = 0; ni < 2; ni++) {
        accg[mi][ni] = __builtin_amdgcn_mfma_f32_16x16x32_bf16(af[mi], bgf[ni], accg[mi][ni], 0, 0, 0);
        accu[mi][ni] = __builtin_amdgcn_mfma_f32_16x16x32_bf16(af[mi], buf2[ni], accu[mi][ni], 0, 0, 0);
      }
  }
  const int rb0 = wm + (lane >> 4) * 4;
  const int cb0 = n0 + wn + fr;
#pragma unroll
  for (int mi = 0; mi < 4; mi++)
#pragma unroll
    for (int ni = 0; ni < 2; ni++)
#pragma unroll
      for (int r = 0; r < 4; r++) {
        int lrow = rb0 + mi * 16 + r;
        int col = cb0 + ni * 16;
        float g = accg[mi][ni][r], u = accu[mi][ni][r];
        float hv = (g / (1.f + __expf(-g))) * u;
        h[(size_t)(ent.z + lrow) * DFF + col] = f32_bf16(hv);
      }
}

// ---------------- unified GEMM2: out[tok] += wsl * (h[slot] @ wd_e)  (out pre-zeroed) ----------------
__global__ __launch_bounds__(256) void gemm2_kernel(
    const unsigned short* __restrict__ h, const unsigned short* __restrict__ wdt,
    const int* __restrict__ idxAll, const float* __restrict__ wslAll,
    const int4* __restrict__ sched, float* __restrict__ out) {
  const int4 ent = sched[blockIdx.y];
  if (ent.x < 0) return;
  __shared__ unsigned short As[128 * 32];
  __shared__ unsigned short Bs[128 * 32];
  const int tid = threadIdx.x, lane = tid & 63, wid = tid >> 6;
  const int n0 = blockIdx.x * 128;
  const int wm = (wid >> 1) * 64, wn = (wid & 1) * 64;
  floatx4 acc[4][4];
  const floatx4 z4 = {0.f, 0.f, 0.f, 0.f};
#pragma unroll
  for (int i = 0; i < 4; i++)
#pragma unroll
    for (int j = 0; j < 4; j++) acc[i][j] = z4;
  const unsigned short* wdt_e = wdt + (size_t)ent.x * DFF * DIM;
  const int srow = tid >> 2, scol = (tid & 3) * 8;
  const unsigned short* ap0 = h + (size_t)(ent.z + srow) * DFF + scol;
  const unsigned short* ap1 = ap0 + (size_t)64 * DFF;
  const unsigned short* bp0 = wdt_e + (size_t)(n0 + srow) * DFF + scol;
  const unsigned short* bp1 = bp0 + (size_t)64 * DFF;
  unsigned short* as0 = As + tid * 8;
  unsigned short* as1 = As + (256 + tid) * 8;
  unsigned short* bs0 = Bs + tid * 8;
  unsigned short* bs1 = Bs + (256 + tid) * 8;
  const int fr = lane & 15, kq = (lane >> 4) * 8;
  for (int k0 = 0; k0 < DFF; k0 += 32) {
    __syncthreads();
    gld16(ap0 + k0, as0); gld16(ap1 + k0, as1);
    gld16(bp0 + k0, bs0); gld16(bp1 + k0, bs1);
    __syncthreads();
    bf16x8 af[4], bf[4];
#pragma unroll
    for (int mi = 0; mi < 4; mi++) af[mi] = *(const bf16x8*)(As + (wm + mi * 16 + fr) * 32 + kq);
#pragma unroll
    for (int ni = 0; ni < 4; ni++) bf[ni] = *(const bf16x8*)(Bs + (wn + ni * 16 + fr) * 32 + kq);
#pragma unroll
    for (int mi = 0; mi < 4; mi++)
#pragma unroll
      for (int ni = 0; ni < 4; ni++)
        acc[mi][ni] = __builtin_amdgcn_mfma_f32_16x16x32_bf16(af[mi], bf[ni], acc[mi][ni], 0, 0, 0);
  }
  const int rb0 = wm + (lane >> 4) * 4;
  const int cb0 = n0 + wn + fr;
#pragma unroll
  for (int mi = 0; mi < 4; mi++)
#pragma unroll
    for (int r = 0; r < 4; r++) {
      int lrow = rb0 + mi * 16 + r;
      int tok = idxAll[ent.y + lrow];
      float s = wslAll[ent.y + lrow];
      if (s != 0.f) {
#pragma unroll
        for (int ni = 0; ni < 4; ni++)
          atomicAdd(&out[(size_t)tok * DIM + cb0 + ni * 16], s * acc[mi][ni][r]);
      }
    }
}

extern "C" void kernel_launch(void* const* d_in, const int* in_sizes, int n_in,
                              void* d_out, int out_size, void* d_ws, size_t ws_size,
                              hipStream_t stream) {
  const float* x  = (const float*)d_in[0];
  const float* rw = (const float*)d_in[1];
  const float* rb = (const float*)d_in[2];
  const float* wg = (const float*)d_in[3];
  const float* wu = (const float*)d_in[4];
  const float* wd = (const float*)d_in[5];
  float* out = (float*)d_out;

  // mode A: disjoint e0+routed h (fully unified single GEMM dispatches)
  // mode B: overlapping h, sequential e0 then routed (R2 structure)
  // mode C: per-expert loop (small ws)
  const bool modeA = ws_size >= (size_t)163321408;
  const bool modeB = !modeA && ws_size >= (size_t)146544192;
  const size_t H_ROWS = modeA ? 13184 : (modeB ? 9088 : 4096);
  const int rsb = modeA ? 4096 : 0;

  char* p = (char*)d_ws;
  unsigned short* xb  = (unsigned short*)p; p += (size_t)T_TOK * DIM * 2;
  unsigned short* h   = (unsigned short*)p; p += H_ROWS * DFF * 2;
  unsigned short* wgt = (unsigned short*)p; p += (size_t)NE * DIM * DFF * 2;
  unsigned short* wut = (unsigned short*)p; p += (size_t)NE * DIM * DFF * 2;
  unsigned short* wdt = (unsigned short*)p; p += (size_t)NE * DIM * DFF * 2;
  int*   idxAll = (int*)p;   p += (size_t)(4096 + NR * 4096) * 4;
  float* wslAll = (float*)p; p += (size_t)(4096 + NR * 4096) * 4;
  int*   cnt = (int*)p;      p += 64;
  int4*  schedAll = (int4*)p; p += 2048;
  int4*  schedP   = (int4*)p; p += 4096;

  cvt_x_kernel<<<dim3(T_TOK * DIM / 4 / 256), 256, 0, stream>>>((const float4*)x, (ushort4*)xb);
  hipMemsetAsync(cnt, 0, 64, stream);
  hipMemsetAsync(out, 0, (size_t)out_size * 4, stream);
  router_kernel<<<dim3(T_TOK / 4), 256, 0, stream>>>(x, rw, rb, idxAll, wslAll, cnt);
  sched_kernel<<<dim3(1), 256, 0, stream>>>(cnt, idxAll, wslAll, schedAll, schedP, rsb);
  transpose_cvt_kernel<<<dim3(64, 32, 24), 256, 0, stream>>>(wg, wu, wd, wgt, wut, wdt);

  if (modeA) {
    gemm1_kernel<<<dim3(DFF / 64, NY), 256, 0, stream>>>(xb, wgt, wut, idxAll, schedAll, h);
    gemm2_kernel<<<dim3(DIM / 128, NY), 256, 0, stream>>>(h, wdt, idxAll, wslAll, schedAll, out);
  } else if (modeB) {
    gemm1_kernel<<<dim3(DFF / 64, 32), 256, 0, stream>>>(xb, wgt, wut, idxAll, schedAll, h);
    gemm2_kernel<<<dim3(DIM / 128, 32), 256, 0, stream>>>(h, wdt, idxAll, wslAll, schedAll, out);
    gemm1_kernel<<<dim3(DFF / 64, MAXNB), 256, 0, stream>>>(xb, wgt, wut, idxAll, schedAll + 32, h);
    gemm2_kernel<<<dim3(DIM / 128, MAXNB), 256, 0, stream>>>(h, wdt, idxAll, wslAll, schedAll + 32, out);
  } else {
    gemm1_kernel<<<dim3(DFF / 64, 32), 256, 0, stream>>>(xb, wgt, wut, idxAll, schedAll, h);
    gemm2_kernel<<<dim3(DIM / 128, 32), 256, 0, stream>>>(h, wdt, idxAll, wslAll, schedAll, out);
    for (int e = 0; e < NR; e++) {
      gemm1_kernel<<<dim3(DFF / 64, 32), 256, 0, stream>>>(xb, wgt, wut, idxAll, schedP + e * 32, h);
      gemm2_kernel<<<dim3(DIM / 128, 32), 256, 0, stream>>>(h, wdt, idxAll, wslAll, schedP + e * 32, out);
    }
  }
}

// Round 5
// 596.469 us; speedup vs baseline: 1.0765x; 1.0516x over previous
//
#include <hip/hip_runtime.h>

// Problem constants (B=2,S=2048,D=1024,E=8,DFF=2048,top_k=2)
#define T_TOK 4096
#define DIM   1024
#define DFF   2048
#define NE    8
#define NR    7    // routed experts (E-1)
#define MAXNB 71   // max routed row-blocks: 8192/128 + 7
#define NY    (32 + MAXNB)   // unified sched entries: 32 e0 + routed

typedef __bf16 bf16x8 __attribute__((ext_vector_type(8)));
typedef float  floatx4 __attribute__((ext_vector_type(4)));

__device__ __forceinline__ unsigned short f32_bf16(float f) {
  union { float f; unsigned int u; } v; v.f = f;
  unsigned int u = v.u;
  unsigned int r = (u + 0x7FFFu + ((u >> 16) & 1u)) >> 16;  // RNE
  return (unsigned short)r;
}

typedef __attribute__((address_space(3))) void lds_void_t;
typedef const __attribute__((address_space(1))) void g_void_t;

__device__ __forceinline__ void gld16(const void* g, void* l) {
  // async global->LDS, 16B/lane; LDS dest = wave-uniform base + lane*16 (m104)
  __builtin_amdgcn_global_load_lds((g_void_t*)g, (lds_void_t*)l, 16, 0, 0);
}

// ---------------- x fp32 -> bf16 ----------------
__global__ __launch_bounds__(256) void cvt_x_kernel(const float4* __restrict__ in,
                                                    ushort4* __restrict__ out) {
  int i = blockIdx.x * 256 + threadIdx.x;
  float4 v = in[i];
  ushort4 o;
  o.x = f32_bf16(v.x); o.y = f32_bf16(v.y);
  o.z = f32_bf16(v.z); o.w = f32_bf16(v.w);
  out[i] = o;
}

// ---------------- router: top-2 -> routed seat lists + per-token records ----------------
__global__ __launch_bounds__(256) void router_kernel(const float* __restrict__ x,
                                                     const float* __restrict__ rw,
                                                     const float* __restrict__ rb,
                                                     int* __restrict__ idxR,
                                                     float* __restrict__ wslR,
                                                     int* __restrict__ cnt,
                                                     int4* __restrict__ tokE,
                                                     float2* __restrict__ tokW) {
  const int lane = threadIdx.x & 63;
  const int t = blockIdx.x * 4 + (threadIdx.x >> 6);  // one wave per token
  const float* xr = x + (size_t)t * DIM;
  float acc[NR];
#pragma unroll
  for (int e = 0; e < NR; e++) acc[e] = 0.f;
  for (int d = lane; d < DIM; d += 64) {
    float xv = xr[d];
#pragma unroll
    for (int e = 0; e < NR; e++) acc[e] += xv * rw[d * NR + e];
  }
#pragma unroll
  for (int off = 32; off > 0; off >>= 1) {
#pragma unroll
    for (int e = 0; e < NR; e++) acc[e] += __shfl_xor(acc[e], off, 64);
  }
  if (lane == 0) {
    float lg[NR];
    float m = -1e30f;
#pragma unroll
    for (int e = 0; e < NR; e++) { lg[e] = acc[e] + rb[e]; m = fmaxf(m, lg[e]); }
    float p[NR], s = 0.f;
#pragma unroll
    for (int e = 0; e < NR; e++) { p[e] = expf(lg[e] - m); s += p[e]; }
#pragma unroll
    for (int e = 0; e < NR; e++) p[e] /= s;
    int i1 = 0;
#pragma unroll
    for (int e = 1; e < NR; e++) if (p[e] > p[i1]) i1 = e;   // ties -> lowest index (jax)
    int i2 = (i1 == 0) ? 1 : 0;
#pragma unroll
    for (int e = 0; e < NR; e++) if (e != i1 && p[e] > p[i2]) i2 = e;
    float w1 = p[i1], w2 = p[i2], sw = w1 + w2;
    float w1n = w1 / sw, w2n = w2 / sw;
    int s1 = atomicAdd(&cnt[i1], 1);
    idxR[i1 * 4096 + s1] = t; wslR[i1 * 4096 + s1] = w1n;
    int s2 = atomicAdd(&cnt[i2], 1);
    idxR[i2 * 4096 + s2] = t; wslR[i2 * 4096 + s2] = w2n;
    int4 te; te.x = i1; te.y = s1; te.z = i2; te.w = s2;
    tokE[t] = te;
    float2 tw; tw.x = w1n; tw.y = w2n;
    tokW[t] = tw;
  }
}

// ---------------- schedule tables ----------------
// ent = (weightIdx 0..7 or -1 sentinel, idxR offset or -1=identity, slot base, 0)
// schedAll[0..31]: e0 identity blocks; schedAll[32..32+MAXNB): routed packed (slot base rsb+y*128)
// schedP[e*32+rb]: per-expert tables (fallback, slot base rb*128)
__global__ __launch_bounds__(256) void sched_kernel(const int* __restrict__ cnt,
                                                    int* __restrict__ idxR,
                                                    float* __restrict__ wslR,
                                                    int4* __restrict__ schedAll,
                                                    int4* __restrict__ schedP,
                                                    int* __restrict__ prefOut,
                                                    int rsb) {
  __shared__ int nb[NR], pref[NR];
  if (threadIdx.x == 0) {
    int p = 0;
    for (int e = 0; e < NR; e++) { int c = cnt[e]; int n = (c + 127) >> 7; nb[e] = n; pref[e] = p; p += n; }
  }
  __syncthreads();
  if (threadIdx.x < NR) prefOut[threadIdx.x] = pref[threadIdx.x];
  for (int e = 0; e < NR; e++) {
    int c = cnt[e], top = nb[e] * 128;
    for (int i = c + (int)threadIdx.x; i < top; i += 256) {
      idxR[e * 4096 + i] = 0; wslR[e * 4096 + i] = 0.f;
    }
  }
  const int NBtot = pref[NR - 1] + nb[NR - 1];
  for (int y = threadIdx.x; y < 32; y += 256) {
    int4 ent; ent.x = 0; ent.y = -1; ent.z = y * 128; ent.w = 0;
    schedAll[y] = ent;
  }
  for (int y = threadIdx.x; y < MAXNB; y += 256) {
    int4 ent; ent.x = -1; ent.y = 0; ent.z = 0; ent.w = 0;
    if (y < NBtot) {
#pragma unroll
      for (int e = 0; e < NR; e++)
        if (y >= pref[e] && y < pref[e] + nb[e]) {
          int rb2 = y - pref[e];
          ent.x = e + 1; ent.y = e * 4096 + rb2 * 128; ent.z = rsb + y * 128;
        }
    }
    schedAll[32 + y] = ent;
  }
  for (int i = threadIdx.x; i < NR * 32; i += 256) {
    int e = i >> 5, rb2 = i & 31;
    int4 ent; ent.w = 0;
    if (rb2 < nb[e]) { ent.x = e + 1; ent.y = e * 4096 + rb2 * 128; ent.z = rb2 * 128; }
    else             { ent.x = -1; ent.y = 0; ent.z = 0; }
    schedP[i] = ent;
  }
}

// ---------------- weight transpose + fp32->bf16 (4B/lane writes) ----------------
__global__ __launch_bounds__(256) void transpose_cvt_kernel(
    const float* __restrict__ wg, const float* __restrict__ wu, const float* __restrict__ wd,
    unsigned short* __restrict__ wgt, unsigned short* __restrict__ wut,
    unsigned short* __restrict__ wdt) {
  __shared__ float tile[64][33];
  const int z = blockIdx.z;
  const float* src; unsigned short* dst; int R, C;
  if (z < 8)       { src = wg + (size_t)z * DIM * DFF;        dst = wgt + (size_t)z * DIM * DFF;        R = DIM; C = DFF; }
  else if (z < 16) { src = wu + (size_t)(z - 8) * DIM * DFF;  dst = wut + (size_t)(z - 8) * DIM * DFF;  R = DIM; C = DFF; }
  else             { src = wd + (size_t)(z - 16) * DFF * DIM; dst = wdt + (size_t)(z - 16) * DFF * DIM; R = DFF; C = DIM; }
  const int c0 = blockIdx.x * 32, r0 = blockIdx.y * 64;
  if (c0 >= C || r0 >= R) return;
  const int tx = threadIdx.x & 31, ty = threadIdx.x >> 5;
#pragma unroll
  for (int j = ty; j < 64; j += 8)
    tile[j][tx] = src[(size_t)(r0 + j) * C + c0 + tx];
  __syncthreads();
#pragma unroll
  for (int j = ty; j < 32; j += 8) {
    unsigned int lo = f32_bf16(tile[2 * tx][j]);
    unsigned int hi = f32_bf16(tile[2 * tx + 1][j]);
    *(unsigned int*)(dst + (size_t)(c0 + j) * R + r0 + 2 * tx) = lo | (hi << 16);
  }
}

// ---------------- GEMM1: h[slot] = silu(x[tok]@wg_e)*(x[tok]@wu_e) ----------------
// BM=128, BN=128 per matrix, BK=32; 4 waves 2x2, each wave 64x64 of BOTH g,u.
__global__ __launch_bounds__(256, 2) void gemm1_kernel(
    const unsigned short* __restrict__ xb, const unsigned short* __restrict__ wgt,
    const unsigned short* __restrict__ wut, const int* __restrict__ idxR,
    const int4* __restrict__ sched, unsigned short* __restrict__ h) {
  const int4 ent = sched[blockIdx.y];
  if (ent.x < 0) return;
  __shared__ unsigned short As[128 * 32];
  __shared__ unsigned short Bg[128 * 32];
  __shared__ unsigned short Bu[128 * 32];
  const int tid = threadIdx.x, lane = tid & 63, wid = tid >> 6;
  const int n0 = blockIdx.x * 128;
  const int wm = (wid >> 1) * 64, wn = (wid & 1) * 64;
  floatx4 accg[4][4], accu[4][4];
  const floatx4 z4 = {0.f, 0.f, 0.f, 0.f};
#pragma unroll
  for (int i = 0; i < 4; i++)
#pragma unroll
    for (int j = 0; j < 4; j++) { accg[i][j] = z4; accu[i][j] = z4; }
  const unsigned short* wgt_e = wgt + (size_t)ent.x * DIM * DFF;
  const unsigned short* wut_e = wut + (size_t)ent.x * DIM * DFF;
  const int srow = tid >> 2, scol = (tid & 3) * 8;
  int tok0, tok1;
  if (ent.y < 0) { tok0 = ent.z + srow; tok1 = ent.z + srow + 64; }
  else           { tok0 = idxR[ent.y + srow]; tok1 = idxR[ent.y + srow + 64]; }
  const unsigned short* ap0 = xb + (size_t)tok0 * DIM + scol;
  const unsigned short* ap1 = xb + (size_t)tok1 * DIM + scol;
  const unsigned short* bg0 = wgt_e + (size_t)(n0 + srow) * DIM + scol;
  const unsigned short* bg1 = bg0 + (size_t)64 * DIM;
  const unsigned short* bu0 = wut_e + (size_t)(n0 + srow) * DIM + scol;
  const unsigned short* bu1 = bu0 + (size_t)64 * DIM;
  unsigned short* as0 = As + tid * 8;
  unsigned short* as1 = As + (256 + tid) * 8;
  unsigned short* bgl0 = Bg + tid * 8;
  unsigned short* bgl1 = Bg + (256 + tid) * 8;
  unsigned short* bul0 = Bu + tid * 8;
  unsigned short* bul1 = Bu + (256 + tid) * 8;
  const int fr = lane & 15, kq = (lane >> 4) * 8;
  for (int k0 = 0; k0 < DIM; k0 += 32) {
    __syncthreads();
    gld16(ap0 + k0, as0); gld16(ap1 + k0, as1);
    gld16(bg0 + k0, bgl0); gld16(bg1 + k0, bgl1);
    gld16(bu0 + k0, bul0); gld16(bu1 + k0, bul1);
    __syncthreads();
    bf16x8 af[4], bgf[4], buf2[4];
#pragma unroll
    for (int mi = 0; mi < 4; mi++) af[mi] = *(const bf16x8*)(As + (wm + mi * 16 + fr) * 32 + kq);
#pragma unroll
    for (int ni = 0; ni < 4; ni++) {
      bgf[ni]  = *(const bf16x8*)(Bg + (wn + ni * 16 + fr) * 32 + kq);
      buf2[ni] = *(const bf16x8*)(Bu + (wn + ni * 16 + fr) * 32 + kq);
    }
#pragma unroll
    for (int mi = 0; mi < 4; mi++)
#pragma unroll
      for (int ni = 0; ni < 4; ni++) {
        accg[mi][ni] = __builtin_amdgcn_mfma_f32_16x16x32_bf16(af[mi], bgf[ni], accg[mi][ni], 0, 0, 0);
        accu[mi][ni] = __builtin_amdgcn_mfma_f32_16x16x32_bf16(af[mi], buf2[ni], accu[mi][ni], 0, 0, 0);
      }
  }
  const int rb0 = wm + (lane >> 4) * 4;
  const int cb0 = n0 + wn + fr;
#pragma unroll
  for (int mi = 0; mi < 4; mi++)
#pragma unroll
    for (int ni = 0; ni < 4; ni++)
#pragma unroll
      for (int r = 0; r < 4; r++) {
        int lrow = rb0 + mi * 16 + r;
        int col = cb0 + ni * 16;
        float g = accg[mi][ni][r], u = accu[mi][ni][r];
        float hv = (g / (1.f + __expf(-g))) * u;
        h[(size_t)(ent.z + lrow) * DFF + col] = f32_bf16(hv);
      }
}

// ---------------- GEMM2 (plain): y[slot] = h[slot] @ wd_e ----------------
// BM=128, BN=128 (m97 shape), no gather/scatter, no atomics.
__global__ __launch_bounds__(256) void gemm2_kernel(
    const unsigned short* __restrict__ h, const unsigned short* __restrict__ wdt,
    const int4* __restrict__ sched, float* __restrict__ y) {
  const int4 ent = sched[blockIdx.y];
  if (ent.x < 0) return;
  __shared__ unsigned short As[128 * 32];
  __shared__ unsigned short Bs[128 * 32];
  const int tid = threadIdx.x, lane = tid & 63, wid = tid >> 6;
  const int n0 = blockIdx.x * 128;
  const int wm = (wid >> 1) * 64, wn = (wid & 1) * 64;
  floatx4 acc[4][4];
  const floatx4 z4 = {0.f, 0.f, 0.f, 0.f};
#pragma unroll
  for (int i = 0; i < 4; i++)
#pragma unroll
    for (int j = 0; j < 4; j++) acc[i][j] = z4;
  const unsigned short* wdt_e = wdt + (size_t)ent.x * DFF * DIM;
  const int srow = tid >> 2, scol = (tid & 3) * 8;
  const unsigned short* ap0 = h + (size_t)(ent.z + srow) * DFF + scol;
  const unsigned short* ap1 = ap0 + (size_t)64 * DFF;
  const unsigned short* bp0 = wdt_e + (size_t)(n0 + srow) * DFF + scol;
  const unsigned short* bp1 = bp0 + (size_t)64 * DFF;
  unsigned short* as0 = As + tid * 8;
  unsigned short* as1 = As + (256 + tid) * 8;
  unsigned short* bs0 = Bs + tid * 8;
  unsigned short* bs1 = Bs + (256 + tid) * 8;
  const int fr = lane & 15, kq = (lane >> 4) * 8;
  for (int k0 = 0; k0 < DFF; k0 += 32) {
    __syncthreads();
    gld16(ap0 + k0, as0); gld16(ap1 + k0, as1);
    gld16(bp0 + k0, bs0); gld16(bp1 + k0, bs1);
    __syncthreads();
    bf16x8 af[4], bf[4];
#pragma unroll
    for (int mi = 0; mi < 4; mi++) af[mi] = *(const bf16x8*)(As + (wm + mi * 16 + fr) * 32 + kq);
#pragma unroll
    for (int ni = 0; ni < 4; ni++) bf[ni] = *(const bf16x8*)(Bs + (wn + ni * 16 + fr) * 32 + kq);
#pragma unroll
    for (int mi = 0; mi < 4; mi++)
#pragma unroll
      for (int ni = 0; ni < 4; ni++)
        acc[mi][ni] = __builtin_amdgcn_mfma_f32_16x16x32_bf16(af[mi], bf[ni], acc[mi][ni], 0, 0, 0);
  }
  const int rb0 = wm + (lane >> 4) * 4;
  const int cb0 = n0 + wn + fr;
#pragma unroll
  for (int mi = 0; mi < 4; mi++)
#pragma unroll
    for (int ni = 0; ni < 4; ni++)
#pragma unroll
      for (int r = 0; r < 4; r++) {
        int lrow = rb0 + mi * 16 + r;
        y[(size_t)(ent.z + lrow) * DIM + cb0 + ni * 16] = acc[mi][ni][r];
      }
}

// ---------------- GEMM2 atomic variant (fallback modes) ----------------
__global__ __launch_bounds__(256) void gemm2_atomic_kernel(
    const unsigned short* __restrict__ h, const unsigned short* __restrict__ wdt,
    const int* __restrict__ idxR, const float* __restrict__ wslR,
    const int4* __restrict__ sched, float* __restrict__ out) {
  const int4 ent = sched[blockIdx.y];
  if (ent.x < 0) return;
  __shared__ unsigned short As[128 * 32];
  __shared__ unsigned short Bs[128 * 32];
  const int tid = threadIdx.x, lane = tid & 63, wid = tid >> 6;
  const int n0 = blockIdx.x * 128;
  const int wm = (wid >> 1) * 64, wn = (wid & 1) * 64;
  floatx4 acc[4][4];
  const floatx4 z4 = {0.f, 0.f, 0.f, 0.f};
#pragma unroll
  for (int i = 0; i < 4; i++)
#pragma unroll
    for (int j = 0; j < 4; j++) acc[i][j] = z4;
  const unsigned short* wdt_e = wdt + (size_t)ent.x * DFF * DIM;
  const int srow = tid >> 2, scol = (tid & 3) * 8;
  const unsigned short* ap0 = h + (size_t)(ent.z + srow) * DFF + scol;
  const unsigned short* ap1 = ap0 + (size_t)64 * DFF;
  const unsigned short* bp0 = wdt_e + (size_t)(n0 + srow) * DFF + scol;
  const unsigned short* bp1 = bp0 + (size_t)64 * DFF;
  unsigned short* as0 = As + tid * 8;
  unsigned short* as1 = As + (256 + tid) * 8;
  unsigned short* bs0 = Bs + tid * 8;
  unsigned short* bs1 = Bs + (256 + tid) * 8;
  const int fr = lane & 15, kq = (lane >> 4) * 8;
  for (int k0 = 0; k0 < DFF; k0 += 32) {
    __syncthreads();
    gld16(ap0 + k0, as0); gld16(ap1 + k0, as1);
    gld16(bp0 + k0, bs0); gld16(bp1 + k0, bs1);
    __syncthreads();
    bf16x8 af[4], bf[4];
#pragma unroll
    for (int mi = 0; mi < 4; mi++) af[mi] = *(const bf16x8*)(As + (wm + mi * 16 + fr) * 32 + kq);
#pragma unroll
    for (int ni = 0; ni < 4; ni++) bf[ni] = *(const bf16x8*)(Bs + (wn + ni * 16 + fr) * 32 + kq);
#pragma unroll
    for (int mi = 0; mi < 4; mi++)
#pragma unroll
      for (int ni = 0; ni < 4; ni++)
        acc[mi][ni] = __builtin_amdgcn_mfma_f32_16x16x32_bf16(af[mi], bf[ni], acc[mi][ni], 0, 0, 0);
  }
  const int rb0 = wm + (lane >> 4) * 4;
  const int cb0 = n0 + wn + fr;
#pragma unroll
  for (int mi = 0; mi < 4; mi++)
#pragma unroll
    for (int r = 0; r < 4; r++) {
      int lrow = rb0 + mi * 16 + r;
      if (ent.y < 0) {
        int tok = ent.z + lrow;
#pragma unroll
        for (int ni = 0; ni < 4; ni++)
          out[(size_t)tok * DIM + cb0 + ni * 16] = acc[mi][ni][r];
      } else {
        int tok = idxR[ent.y + lrow];
        float s = wslR[ent.y + lrow];
        if (s != 0.f) {
#pragma unroll
          for (int ni = 0; ni < 4; ni++)
            atomicAdd(&out[(size_t)tok * DIM + cb0 + ni * 16], s * acc[mi][ni][r]);
        }
      }
    }
}

// ---------------- combine: out[t] = y[t] + w1*y[p1] + w2*y[p2] ----------------
__global__ __launch_bounds__(256) void combine_kernel(const float* __restrict__ y,
                                                      const int4* __restrict__ tokE,
                                                      const float2* __restrict__ tokW,
                                                      const int* __restrict__ pref,
                                                      float* __restrict__ out) {
  const int t = blockIdx.x;
  const int c = threadIdx.x * 4;
  int4 te = tokE[t];
  float2 tw = tokW[t];
  int p1 = 4096 + pref[te.x] * 128 + te.y;
  int p2 = 4096 + pref[te.z] * 128 + te.w;
  float4 a = *(const float4*)(y + (size_t)t * DIM + c);
  float4 b = *(const float4*)(y + (size_t)p1 * DIM + c);
  float4 d = *(const float4*)(y + (size_t)p2 * DIM + c);
  float4 o;
  o.x = a.x + tw.x * b.x + tw.y * d.x;
  o.y = a.y + tw.x * b.y + tw.y * d.y;
  o.z = a.z + tw.x * b.z + tw.y * d.z;
  o.w = a.w + tw.x * b.w + tw.y * d.w;
  *(float4*)(out + (size_t)t * DIM + c) = o;
}

extern "C" void kernel_launch(void* const* d_in, const int* in_sizes, int n_in,
                              void* d_out, int out_size, void* d_ws, size_t ws_size,
                              hipStream_t stream) {
  const float* x  = (const float*)d_in[0];
  const float* rw = (const float*)d_in[1];
  const float* rb = (const float*)d_in[2];
  const float* wg = (const float*)d_in[3];
  const float* wu = (const float*)d_in[4];
  const float* wd = (const float*)d_in[5];
  float* out = (float*)d_out;

  // mode A2: unified, atomic-free (y aliases dead wgt/wut); needs ~163.28 MB (ws known >= 163.32 MB)
  // mode B : sequential e0 + routed, atomic gemm2; needs ~146.7 MB
  // mode C : per-expert loop, atomic gemm2
  const bool modeA = ws_size >= (size_t)163300000;
  const bool modeB = !modeA && ws_size >= (size_t)146700000;
  const size_t H_ROWS = modeA ? 13184 : (modeB ? 9088 : 4096);
  const int rsb = modeA ? 4096 : 0;

  char* p = (char*)d_ws;
  unsigned short* xb  = (unsigned short*)p; p += (size_t)T_TOK * DIM * 2;       // 8,388,608
  unsigned short* h   = (unsigned short*)p; p += H_ROWS * DFF * 2;
  unsigned short* wgt = (unsigned short*)p;                                     // y aliases wgt+wut in mode A
  float*          y   = (float*)p;          p += (size_t)NE * DIM * DFF * 2;
  unsigned short* wut = (unsigned short*)p; p += (size_t)NE * DIM * DFF * 2;
  unsigned short* wdt = (unsigned short*)p; p += (size_t)NE * DIM * DFF * 2;
  int*   idxR = (int*)p;   p += (size_t)NR * 4096 * 4;                          // 114,688
  float* wslR;
  if (modeA) { wslR = (float*)wdt; }                                            // scratch: overwritten by transpose later
  else       { wslR = (float*)p; p += (size_t)NR * 4096 * 4; }
  int*   cnt  = (int*)p;      p += 64;
  int*   pref = (int*)p;      p += 64;
  int4*  schedAll = (int4*)p; p += 2048;
  int4*  schedP   = (int4*)p; p += 4096;
  int4*  tokE = (int4*)p;     p += (size_t)T_TOK * 16;
  float2* tokW = (float2*)p;  p += (size_t)T_TOK * 8;

  cvt_x_kernel<<<dim3(T_TOK * DIM / 4 / 256), 256, 0, stream>>>((const float4*)x, (ushort4*)xb);
  hipMemsetAsync(cnt, 0, 64, stream);
  router_kernel<<<dim3(T_TOK / 4), 256, 0, stream>>>(x, rw, rb, idxR, wslR, cnt, tokE, tokW);
  sched_kernel<<<dim3(1), 256, 0, stream>>>(cnt, idxR, wslR, schedAll, schedP, pref, rsb);
  transpose_cvt_kernel<<<dim3(64, 32, 24), 256, 0, stream>>>(wg, wu, wd, wgt, wut, wdt);

  if (modeA) {
    gemm1_kernel<<<dim3(DFF / 128, NY), 256, 0, stream>>>(xb, wgt, wut, idxR, schedAll, h);
    gemm2_kernel<<<dim3(DIM / 128, NY), 256, 0, stream>>>(h, wdt, schedAll, y);
    combine_kernel<<<dim3(T_TOK), 256, 0, stream>>>(y, tokE, tokW, pref, out);
  } else if (modeB) {
    gemm1_kernel<<<dim3(DFF / 128, 32), 256, 0, stream>>>(xb, wgt, wut, idxR, schedAll, h);
    gemm2_atomic_kernel<<<dim3(DIM / 128, 32), 256, 0, stream>>>(h, wdt, idxR, wslR, schedAll, out);
    gemm1_kernel<<<dim3(DFF / 128, MAXNB), 256, 0, stream>>>(xb, wgt, wut, idxR, schedAll + 32, h);
    gemm2_atomic_kernel<<<dim3(DIM / 128, MAXNB), 256, 0, stream>>>(h, wdt, idxR, wslR, schedAll + 32, out);
  } else {
    gemm1_kernel<<<dim3(DFF / 128, 32), 256, 0, stream>>>(xb, wgt, wut, idxR, schedAll, h);
    gemm2_atomic_kernel<<<dim3(DIM / 128, 32), 256, 0, stream>>>(h, wdt, idxR, wslR, schedAll, out);
    for (int e = 0; e < NR; e++) {
      gemm1_kernel<<<dim3(DFF / 128, 32), 256, 0, stream>>>(xb, wgt, wut, idxR, schedP + e * 32, h);
      gemm2_atomic_kernel<<<dim3(DIM / 128, 32), 256, 0, stream>>>(h, wdt, idxR, wslR, schedP + e * 32, out);
    }
  }
}